// Round 7
// baseline (1002.496 us; speedup 1.0000x reference)
//
#include <hip/hip_runtime.h>
#include <stdint.h>

#define TT   500
#define BB   64
#define IND  256
#define HD   512
#define ROWS (TT*BB)   // 32000

typedef __attribute__((ext_vector_type(8))) short sh8;   // 8 bf16
typedef __attribute__((ext_vector_type(4))) float f32x4;

#define SCALE_F ((float)((1.0 - 0.001) / 31.0))

__device__ __forceinline__ void load16_lds(const uint16_t* g, uint16_t* l) {
  __builtin_amdgcn_global_load_lds((const __attribute__((address_space(1))) void*)g,
                                   (__attribute__((address_space(3))) void*)l, 16, 0, 0);
}

__device__ __forceinline__ int bsum4(uint32_t w) {
  return (int)((w & 0xff) + ((w >> 8) & 0xff) + ((w >> 16) & 0xff) + (w >> 24));
}

// ---------------- prep: quantized-weight build (exact np math)
__device__ __forceinline__ void prep_one(int id,
                                         const float* W1, const float* W2,
                                         const float* W3, const float* W4,
                                         uint16_t* wk1, uint16_t* wk2,
                                         uint16_t* wk3, uint16_t* wk4) {
  const float* W; uint16_t* wk; int idx, K, H;
  if (id < 131072)       { idx = id;          W = W1; wk = wk1; K = 256; H = 512; }
  else if (id < 393216)  { idx = id - 131072; W = W2; wk = wk2; K = 512; H = 512; }
  else if (id < 655360)  { idx = id - 393216; W = W3; wk = wk3; K = 512; H = 512; }
  else                   { idx = id - 655360; W = W4; wk = wk4; K = 512; H = 35;  }
  int h = idx / K;
  int k = idx - h * K;
  uint16_t bits = 0;
  if (h < H) {
    float w  = W[h * K + k];
    float wc = fminf(1.0f, fmaxf(0.001f, w));
    float v  = (wc - 0.001f) / SCALE_F;
    float q  = rintf(v);                            // round-half-even = np.round
    bits = (uint16_t)(__float_as_uint(q) >> 16);    // small ints exact in bf16
  }
  wk[idx] = bits;
}

// ---------------- fused prep + cochlea
// blocks 0..2815: prep. blocks 2816..2879: cochlea (one block per b, 256 thr).
// Cochlea writes bf16 spikes [row][256] + per-wave count BYTE n4[row*4+wv].
__global__ __launch_bounds__(256) void k_prep_coch(const float* __restrict__ W1,
                                                   const float* __restrict__ W2,
                                                   const float* __restrict__ W3,
                                                   const float* __restrict__ W4,
                                                   uint16_t* __restrict__ wk1,
                                                   uint16_t* __restrict__ wk2,
                                                   uint16_t* __restrict__ wk3,
                                                   uint16_t* __restrict__ wk4,
                                                   const float* __restrict__ x,
                                                   const float* __restrict__ Wch,
                                                   const float* __restrict__ cbetas,
                                                   uint16_t* __restrict__ chs,
                                                   uint8_t* __restrict__ n4) {
  __shared__ float xs[TT];
  int g = blockIdx.x, t = threadIdx.x;
  if (g < 2816) {
    int id = g * 256 + t;
    if (id < 720896) prep_one(id, W1, W2, W3, W4, wk1, wk2, wk3, wk4);
    return;
  }
  int b = g - 2816;
  for (int tt = t; tt < TT; tt += 256) xs[tt] = x[b * TT + tt];
  __syncthreads();
  int wv = t >> 6, lane = t & 63;
  float w    = Wch[t];
  float beta = fminf(1.0f, fmaxf(0.0f, cbetas[t]));
  float mem  = 0.0f;
  for (int tt = 0; tt < TT; ++tt) {
    float cur = __fmul_rn(xs[tt], w);
    int   rs  = (mem > 1.0f);
    float t2  = __fadd_rn(__fmul_rn(beta, mem), cur);
    mem = rs ? __fsub_rn(t2, 1.0f) : t2;
    int spk = (mem > 1.0f);
    int row = tt * BB + b;
    chs[(size_t)row * IND + t] = spk ? 0x3F80 : 0;
    unsigned long long bal = __ballot(spk);
    if (lane == 0) n4[(size_t)row * 4 + wv] = (uint8_t)__popcll(bal);
  }
}

// ---------------- R3-proven LDS MFMA GEMM: 128x128 tile, 4 waves (64x64 each)
// global_load_lds width-16 staging, XOR bank swizzle. Exact integer bf16 MFMA.
template<int K>
__global__ __launch_bounds__(256) void k_gemm_lds(const uint16_t* __restrict__ A,
                                                  const uint16_t* __restrict__ B,
                                                  uint16_t* __restrict__ M,
                                                  int Hp, int coltiles) {
  __shared__ uint16_t As[128 * 64];
  __shared__ uint16_t Bs[128 * 64];
  int tid  = threadIdx.x;
  int lane = tid & 63, w = tid >> 6;
  int rt = blockIdx.x / coltiles, ct = blockIdx.x - rt * coltiles;
  int r0 = rt * 128, c0 = ct * 128;
  int wr = (w >> 1) * 64, wc = (w & 1) * 64;
  int lr = lane & 15, kgf = lane >> 4;
  f32x4 acc[4][4];
#pragma unroll
  for (int i = 0; i < 4; ++i)
#pragma unroll
    for (int j = 0; j < 4; ++j) acc[i][j] = (f32x4){0, 0, 0, 0};

  for (int k0 = 0; k0 < K; k0 += 64) {
    __syncthreads();
#pragma unroll
    for (int i = 0; i < 4; ++i) {
      int L = i * 256 + tid;
      int row = L >> 3, c = L & 7;
      int kg = c ^ (row & 7);
      load16_lds(A + (size_t)(r0 + row) * K + k0 + kg * 8, &As[(i * 256 + w * 64) * 8]);
    }
#pragma unroll
    for (int i = 0; i < 4; ++i) {
      int L = i * 256 + tid;
      int row = L >> 3, c = L & 7;
      int kg = c ^ (row & 7);
      load16_lds(B + (size_t)(c0 + row) * K + k0 + kg * 8, &Bs[(i * 256 + w * 64) * 8]);
    }
    __syncthreads();
#pragma unroll
    for (int kk = 0; kk < 2; ++kk) {
      sh8 a[4], b[4];
#pragma unroll
      for (int s = 0; s < 4; ++s) {
        int arow = wr + s * 16 + lr;
        int sa   = (kk * 4 + kgf) ^ (arow & 7);
        a[s] = *(const sh8*)&As[arow * 64 + sa * 8];
        int brow = wc + s * 16 + lr;
        int sb   = (kk * 4 + kgf) ^ (brow & 7);
        b[s] = *(const sh8*)&Bs[brow * 64 + sb * 8];
      }
#pragma unroll
      for (int ar = 0; ar < 4; ++ar)
#pragma unroll
        for (int cs = 0; cs < 4; ++cs)
          acc[ar][cs] = __builtin_amdgcn_mfma_f32_16x16x32_bf16(a[ar], b[cs], acc[ar][cs], 0, 0, 0);
    }
  }
  int oc = lane & 15;
  int rb = (lane >> 4) * 4;
#pragma unroll
  for (int ar = 0; ar < 4; ++ar)
#pragma unroll
    for (int i = 0; i < 4; ++i) {
      size_t rowoff = (size_t)(r0 + wr + ar * 16 + rb + i) * Hp;
#pragma unroll
      for (int cs = 0; cs < 4; ++cs)
        M[rowoff + c0 + wc + cs * 16 + oc] = (uint16_t)acc[ar][cs][i];
    }
}

// ---------------- naive 64x64-per-wave GEMM (layer 4)
template<int K>
__global__ __launch_bounds__(256) void k_gemm_naive(const uint16_t* __restrict__ A,
                                                    const uint16_t* __restrict__ B,
                                                    uint16_t* __restrict__ M,
                                                    int Hp) {
  int wid  = (blockIdx.x * 256 + threadIdx.x) >> 6;
  int lane = threadIdx.x & 63;
  int r0 = wid * 64, c0 = 0;
  int lr = lane & 15;
  int lk = (lane >> 4) * 8;
  const uint16_t* ap = A + (size_t)(r0 + lr) * K + lk;
  const uint16_t* bp = B + (size_t)(c0 + lr) * K + lk;
  f32x4 acc[4][4];
#pragma unroll
  for (int i = 0; i < 4; ++i)
#pragma unroll
    for (int j = 0; j < 4; ++j) acc[i][j] = (f32x4){0, 0, 0, 0};
#pragma unroll 2
  for (int k = 0; k < K / 32; ++k) {
    sh8 a[4], b[4];
#pragma unroll
    for (int s = 0; s < 4; ++s) {
      a[s] = *(const sh8*)(ap + (size_t)s * 16 * K + k * 32);
      b[s] = *(const sh8*)(bp + (size_t)s * 16 * K + k * 32);
    }
#pragma unroll
    for (int ar = 0; ar < 4; ++ar)
#pragma unroll
      for (int cs = 0; cs < 4; ++cs)
        acc[ar][cs] = __builtin_amdgcn_mfma_f32_16x16x32_bf16(a[ar], b[cs], acc[ar][cs], 0, 0, 0);
  }
  int oc = lane & 15;
  int rb = (lane >> 4) * 4;
#pragma unroll
  for (int ar = 0; ar < 4; ++ar)
#pragma unroll
    for (int i = 0; i < 4; ++i) {
      size_t rowoff = (size_t)(r0 + ar * 16 + rb + i) * Hp;
#pragma unroll
      for (int cs = 0; cs < 4; ++cs)
        M[rowoff + c0 + cs * 16 + oc] = (uint16_t)acc[ar][cs][i];
    }
}

// ---------------- LIF scan, H=512: one block per b (512 thr), h = threadIdx.
// Reads producer's byte-partial counts (NPREV=4 cochlea / 8 scan); writes
// spk (f32), s_out (bf16), and its own byte partials n8. No atomics. Idempotent.
template<int NPREV>
__global__ __launch_bounds__(512) void k_scan512(const uint16_t* __restrict__ M,
                                                 const uint8_t* __restrict__ nprev,
                                                 const float* __restrict__ pbeta,
                                                 float* __restrict__ spk_out,
                                                 uint16_t* __restrict__ s_out,
                                                 uint8_t* __restrict__ n8) {
  int h = threadIdx.x, b = blockIdx.x;
  int wv = h >> 6, lane = h & 63;
  float beta = fminf(1.0f, fmaxf(0.0f, *pbeta));
  const double DSCALE = (double)SCALE_F;
  const double DWMIN  = (double)0.001f;
  float mem = 0.0f;
  uint16_t mvA[10], mvB[10]; int nvA[10], nvB[10];
#pragma unroll
  for (int j = 0; j < 10; ++j) {
    int row = j * BB + b;
    mvA[j] = M[(size_t)row * HD + h];
    if (NPREV == 4) nvA[j] = bsum4(*(const uint32_t*)(nprev + (size_t)row * 4));
    else { const uint32_t* pw = (const uint32_t*)(nprev + (size_t)row * 8);
           nvA[j] = bsum4(pw[0]) + bsum4(pw[1]); }
  }
  for (int t0 = 0; t0 < TT; t0 += 10) {
    if (t0 + 10 < TT) {
#pragma unroll
      for (int j = 0; j < 10; ++j) {
        int row = (t0 + 10 + j) * BB + b;
        mvB[j] = M[(size_t)row * HD + h];
        if (NPREV == 4) nvB[j] = bsum4(*(const uint32_t*)(nprev + (size_t)row * 4));
        else { const uint32_t* pw = (const uint32_t*)(nprev + (size_t)row * 8);
               nvB[j] = bsum4(pw[0]) + bsum4(pw[1]); }
      }
    }
#pragma unroll
    for (int j = 0; j < 10; ++j) {
      int tt = t0 + j;
      int row = tt * BB + b;
      float cur = (float)((double)mvA[j] * DSCALE + (double)nvA[j] * DWMIN);
      int   rs  = (mem > 1.0f);
      float t2  = __fadd_rn(__fmul_rn(beta, mem), cur);
      mem = rs ? __fsub_rn(t2, 1.0f) : t2;
      int spk = (mem > 1.0f);
      spk_out[(size_t)tt * (BB * HD) + b * HD + h] = spk ? 1.0f : 0.0f;
      s_out[(size_t)row * HD + h] = spk ? 0x3F80 : 0;
      unsigned long long bal = __ballot(spk);
      if (lane == 0) n8[(size_t)row * 8 + wv] = (uint8_t)__popcll(bal);
    }
#pragma unroll
    for (int j = 0; j < 10; ++j) { mvA[j] = mvB[j]; nvA[j] = nvB[j]; }
  }
}

// ---------------- LIF scan, layer 4 (H=35, Hp=64, writes spk4 + mem4)
__global__ __launch_bounds__(64) void k_scanl4(const uint16_t* __restrict__ M,
                                               const uint8_t* __restrict__ nprev,
                                               const float* __restrict__ pbeta,
                                               float* __restrict__ spk_out,
                                               float* __restrict__ mem_out) {
  int c = blockIdx.x * 64 + threadIdx.x;
  if (c >= BB * 35) return;
  int b = c / 35;
  int h = c - b * 35;
  float beta = fminf(1.0f, fmaxf(0.0f, *pbeta));
  const double DSCALE = (double)SCALE_F;
  const double DWMIN  = (double)0.001f;
  float mem = 0.0f;
  for (int t0 = 0; t0 < TT; t0 += 10) {
    uint16_t mv[10]; int nv[10];
#pragma unroll
    for (int j = 0; j < 10; ++j) {
      int row = (t0 + j) * BB + b;
      mv[j] = M[(size_t)row * 64 + h];
      const uint32_t* pw = (const uint32_t*)(nprev + (size_t)row * 8);
      nv[j] = bsum4(pw[0]) + bsum4(pw[1]);
    }
#pragma unroll
    for (int j = 0; j < 10; ++j) {
      int tt = t0 + j;
      float cur = (float)((double)mv[j] * DSCALE + (double)nv[j] * DWMIN);
      int   rs  = (mem > 1.0f);
      float t2  = __fadd_rn(__fmul_rn(beta, mem), cur);
      mem = rs ? __fsub_rn(t2, 1.0f) : t2;
      int spk = (mem > 1.0f);
      spk_out[(size_t)tt * (BB * 35) + c] = spk ? 1.0f : 0.0f;
      mem_out[(size_t)tt * (BB * 35) + c] = mem;
    }
  }
}

// ---------------- launch
extern "C" void kernel_launch(void* const* d_in, const int* in_sizes, int n_in,
                              void* d_out, int out_size, void* d_ws, size_t ws_size,
                              hipStream_t stream) {
  const float* x      = (const float*)d_in[0];
  const float* Wch    = (const float*)d_in[1];
  const float* W1     = (const float*)d_in[2];
  const float* W2     = (const float*)d_in[3];
  const float* W3     = (const float*)d_in[4];
  const float* W4     = (const float*)d_in[5];
  const float* cbetas = (const float*)d_in[6];
  const float* b1     = (const float*)d_in[7];
  const float* b2     = (const float*)d_in[8];
  const float* b3     = (const float*)d_in[9];
  const float* b4     = (const float*)d_in[10];

  uint8_t* ws = (uint8_t*)d_ws;
  uint16_t* wk1  = (uint16_t*)(ws + 0);          // 512*256*2
  uint16_t* wk2  = (uint16_t*)(ws + 262144);     // 512*512*2
  uint16_t* wk3  = (uint16_t*)(ws + 786432);
  uint16_t* wk4  = (uint16_t*)(ws + 1310720);    // 64*512*2 (rows>=35 zero)
  uint8_t*  n4c  = (uint8_t*)(ws + 1441792);     // 32000*4 bytes
  uint8_t*  n1   = (uint8_t*)(ws + 1569792);     // 32000*8 bytes each
  uint8_t*  n2   = (uint8_t*)(ws + 1825792);
  uint8_t*  n3   = (uint8_t*)(ws + 2081792);     // ends 2337792
  uint16_t* chs  = (uint16_t*)(ws + 2337792);    // 32000*256*2
  uint16_t* sbuf = (uint16_t*)(ws + 18721792);   // 32000*512*2
  uint16_t* mbuf = (uint16_t*)(ws + 51489792);   // 32000*512*2

  float* out  = (float*)d_out;
  float* spk1 = out;
  float* spk2 = out + 16384000;
  float* spk3 = out + 32768000;
  float* spk4 = out + 49152000;
  float* mem4 = out + 50272000;

  k_prep_coch<<<2880, 256, 0, stream>>>(W1, W2, W3, W4, wk1, wk2, wk3, wk4,
                                        x, Wch, cbetas, chs, n4c);

  // === amplification x4 on the three big GEMMs (idempotent) — attribution ===
  for (int rep = 0; rep < 4; ++rep)
    k_gemm_lds<256><<<1000, 256, 0, stream>>>(chs, wk1, mbuf, HD, 4);
  k_scan512<4><<<64, 512, 0, stream>>>(mbuf, n4c, b1, spk1, sbuf, n1);

  for (int rep = 0; rep < 4; ++rep)
    k_gemm_lds<512><<<1000, 256, 0, stream>>>(sbuf, wk2, mbuf, HD, 4);
  k_scan512<8><<<64, 512, 0, stream>>>(mbuf, n1, b2, spk2, sbuf, n2);

  for (int rep = 0; rep < 4; ++rep)
    k_gemm_lds<512><<<1000, 256, 0, stream>>>(sbuf, wk3, mbuf, HD, 4);
  k_scan512<8><<<64, 512, 0, stream>>>(mbuf, n2, b3, spk3, sbuf, n3);

  k_gemm_naive<512><<<125, 256, 0, stream>>>(sbuf, wk4, mbuf, 64);
  k_scanl4<<<35, 64, 0, stream>>>(mbuf, n3, b4, spk4, mem4);
}

// Round 8
// 677.641 us; speedup vs baseline: 1.4794x; 1.4794x over previous
//
#include <hip/hip_runtime.h>
#include <stdint.h>

#define TT   500
#define BB   64
#define IND  256
#define HD   512
#define ROWS (TT*BB)   // 32000, row = b*500 + t (b-major)

typedef __attribute__((ext_vector_type(8))) short sh8;   // 8 bf16
typedef __attribute__((ext_vector_type(4))) float f32x4;

#define SCALE_F ((float)((1.0 - 0.001) / 31.0))
#define GLDS(g, l) __builtin_amdgcn_global_load_lds( \
    (const __attribute__((address_space(1))) void*)(g), \
    (__attribute__((address_space(3))) void*)(l), 16, 0, 0)

__device__ __forceinline__ int bsum4(uint32_t w) {
  return (int)((w & 0xff) + ((w >> 8) & 0xff) + ((w >> 16) & 0xff) + (w >> 24));
}

// ---------------- prep: quantized-weight build (exact np math)
__device__ __forceinline__ void prep_one(int id,
                                         const float* W1, const float* W2,
                                         const float* W3, const float* W4,
                                         uint16_t* wk1, uint16_t* wk2,
                                         uint16_t* wk3, uint16_t* wk4) {
  const float* W; uint16_t* wk; int idx, K, H;
  if (id < 131072)       { idx = id;          W = W1; wk = wk1; K = 256; H = 512; }
  else if (id < 393216)  { idx = id - 131072; W = W2; wk = wk2; K = 512; H = 512; }
  else if (id < 655360)  { idx = id - 393216; W = W3; wk = wk3; K = 512; H = 512; }
  else                   { idx = id - 655360; W = W4; wk = wk4; K = 512; H = 35;  }
  int h = idx / K;
  int k = idx - h * K;
  uint16_t bits = 0;
  if (h < H) {
    float w  = W[h * K + k];
    float wc = fminf(1.0f, fmaxf(0.001f, w));
    float v  = (wc - 0.001f) / SCALE_F;
    float q  = rintf(v);                            // round-half-even = np.round
    bits = (uint16_t)(__float_as_uint(q) >> 16);    // small ints exact in bf16
  }
  wk[idx] = bits;
}

// ---------------- fused prep + cochlea (b-major rows)
__global__ __launch_bounds__(256) void k_prep_coch(const float* __restrict__ W1,
                                                   const float* __restrict__ W2,
                                                   const float* __restrict__ W3,
                                                   const float* __restrict__ W4,
                                                   uint16_t* __restrict__ wk1,
                                                   uint16_t* __restrict__ wk2,
                                                   uint16_t* __restrict__ wk3,
                                                   uint16_t* __restrict__ wk4,
                                                   const float* __restrict__ x,
                                                   const float* __restrict__ Wch,
                                                   const float* __restrict__ cbetas,
                                                   uint16_t* __restrict__ chs,
                                                   uint8_t* __restrict__ n4) {
  __shared__ float xs[TT];
  int g = blockIdx.x, t = threadIdx.x;
  if (g < 2816) {
    int id = g * 256 + t;
    if (id < 720896) prep_one(id, W1, W2, W3, W4, wk1, wk2, wk3, wk4);
    return;
  }
  int b = g - 2816;
  for (int tt = t; tt < TT; tt += 256) xs[tt] = x[b * TT + tt];
  __syncthreads();
  int wv = t >> 6, lane = t & 63;
  float w    = Wch[t];
  float beta = fminf(1.0f, fmaxf(0.0f, cbetas[t]));
  float mem  = 0.0f;
  for (int tt = 0; tt < TT; ++tt) {
    float cur = __fmul_rn(xs[tt], w);
    int   rs  = (mem > 1.0f);
    float t2  = __fadd_rn(__fmul_rn(beta, mem), cur);
    mem = rs ? __fsub_rn(t2, 1.0f) : t2;
    int spk = (mem > 1.0f);
    int row = b * TT + tt;                          // b-major
    chs[(size_t)row * IND + t] = spk ? 0x3F80 : 0;
    unsigned long long bal = __ballot(spk);
    if (lane == 0) n4[(size_t)row * 4 + wv] = (uint8_t)__popcll(bal);
  }
}

// ---------------- R3-proven LDS MFMA GEMM: 128x128 tile, 4 waves (64x64 each)
// Output M is column-GROUPED: M[ct][row][128] (ct = blockIdx%coltiles).
template<int K>
__global__ __launch_bounds__(256) void k_gemm_lds(const uint16_t* __restrict__ A,
                                                  const uint16_t* __restrict__ B,
                                                  uint16_t* __restrict__ M,
                                                  int coltiles) {
  __shared__ uint16_t As[128 * 64];
  __shared__ uint16_t Bs[128 * 64];
  int tid  = threadIdx.x;
  int lane = tid & 63, w = tid >> 6;
  int rt = blockIdx.x / coltiles, ct = blockIdx.x - rt * coltiles;
  int r0 = rt * 128, c0 = ct * 128;
  int wr = (w >> 1) * 64, wc = (w & 1) * 64;
  int lr = lane & 15, kgf = lane >> 4;
  f32x4 acc[4][4];
#pragma unroll
  for (int i = 0; i < 4; ++i)
#pragma unroll
    for (int j = 0; j < 4; ++j) acc[i][j] = (f32x4){0, 0, 0, 0};

  for (int k0 = 0; k0 < K; k0 += 64) {
    __syncthreads();
#pragma unroll
    for (int i = 0; i < 4; ++i) {
      int L = i * 256 + tid;
      int row = L >> 3, c = L & 7;
      int kg = c ^ (row & 7);
      GLDS(A + (size_t)(r0 + row) * K + k0 + kg * 8, &As[(i * 256 + w * 64) * 8]);
    }
#pragma unroll
    for (int i = 0; i < 4; ++i) {
      int L = i * 256 + tid;
      int row = L >> 3, c = L & 7;
      int kg = c ^ (row & 7);
      GLDS(B + (size_t)(c0 + row) * K + k0 + kg * 8, &Bs[(i * 256 + w * 64) * 8]);
    }
    __syncthreads();
#pragma unroll
    for (int kk = 0; kk < 2; ++kk) {
      sh8 a[4], b[4];
#pragma unroll
      for (int s = 0; s < 4; ++s) {
        int arow = wr + s * 16 + lr;
        int sa   = (kk * 4 + kgf) ^ (arow & 7);
        a[s] = *(const sh8*)&As[arow * 64 + sa * 8];
        int brow = wc + s * 16 + lr;
        int sb   = (kk * 4 + kgf) ^ (brow & 7);
        b[s] = *(const sh8*)&Bs[brow * 64 + sb * 8];
      }
#pragma unroll
      for (int ar = 0; ar < 4; ++ar)
#pragma unroll
        for (int cs = 0; cs < 4; ++cs)
          acc[ar][cs] = __builtin_amdgcn_mfma_f32_16x16x32_bf16(a[ar], b[cs], acc[ar][cs], 0, 0, 0);
    }
  }
  // C/D layout: col = lane&15, row = (lane>>4)*4 + reg; grouped store
  int oc = lane & 15;
  int rb = (lane >> 4) * 4;
#pragma unroll
  for (int ar = 0; ar < 4; ++ar)
#pragma unroll
    for (int i = 0; i < 4; ++i) {
      size_t rowoff = ((size_t)ct * ROWS + (r0 + wr + ar * 16 + rb + i)) * 128;
#pragma unroll
      for (int cs = 0; cs < 4; ++cs)
        M[rowoff + wc + cs * 16 + oc] = (uint16_t)acc[ar][cs][i];
    }
}

// ---------------- naive 64x64-per-wave GEMM (layer 4): M4[row][64]
template<int K>
__global__ __launch_bounds__(256) void k_gemm_naive(const uint16_t* __restrict__ A,
                                                    const uint16_t* __restrict__ B,
                                                    uint16_t* __restrict__ M) {
  int wid  = (blockIdx.x * 256 + threadIdx.x) >> 6;
  int lane = threadIdx.x & 63;
  int r0 = wid * 64;
  int lr = lane & 15;
  int lk = (lane >> 4) * 8;
  const uint16_t* ap = A + (size_t)(r0 + lr) * K + lk;
  const uint16_t* bp = B + (size_t)lr * K + lk;
  f32x4 acc[4][4];
#pragma unroll
  for (int i = 0; i < 4; ++i)
#pragma unroll
    for (int j = 0; j < 4; ++j) acc[i][j] = (f32x4){0, 0, 0, 0};
#pragma unroll 2
  for (int k = 0; k < K / 32; ++k) {
    sh8 a[4], b[4];
#pragma unroll
    for (int s = 0; s < 4; ++s) {
      a[s] = *(const sh8*)(ap + (size_t)s * 16 * K + k * 32);
      b[s] = *(const sh8*)(bp + (size_t)s * 16 * K + k * 32);
    }
#pragma unroll
    for (int ar = 0; ar < 4; ++ar)
#pragma unroll
      for (int cs = 0; cs < 4; ++cs)
        acc[ar][cs] = __builtin_amdgcn_mfma_f32_16x16x32_bf16(a[ar], b[cs], acc[ar][cs], 0, 0, 0);
  }
  int oc = lane & 15;
  int rb = (lane >> 4) * 4;
#pragma unroll
  for (int ar = 0; ar < 4; ++ar)
#pragma unroll
    for (int i = 0; i < 4; ++i) {
      size_t rowoff = (size_t)(r0 + ar * 16 + rb + i) * 64;
#pragma unroll
      for (int cs = 0; cs < 4; ++cs)
        M[rowoff + cs * 16 + oc] = (uint16_t)acc[ar][cs][i];
    }
}

// ---------------- LIF scan, H=512: 256 blocks (b x 4 hgroups) x 128 thr.
// Input M grouped [hg][row][128], b-major rows -> contiguous 128 KB slice.
// Double-buffered LDS chunks (64 t) staged via global_load_lds. np-exact math.
template<int NPREV>
__global__ __launch_bounds__(128) void k_scan512(const uint16_t* __restrict__ Mh,
                                                 const uint8_t* __restrict__ nprev,
                                                 const float* __restrict__ pbeta,
                                                 float* __restrict__ spk_out,
                                                 uint16_t* __restrict__ s_out,
                                                 uint8_t* __restrict__ n8) {
  __shared__ uint16_t Ml[2][64 * 128];   // 2 x 16 KB
  __shared__ uint8_t  Nl[2][1024];       // 2 x 1 KB
  int tid = threadIdx.x;
  int b = blockIdx.x >> 2, hg = blockIdx.x & 3;
  int h = hg * 128 + tid;
  int wv = tid >> 6, lane = tid & 63;
  int wv_g = hg * 2 + wv;
  const uint8_t* Mg = (const uint8_t*)Mh + ((size_t)hg * ROWS + (size_t)b * TT) * 256;
  const uint8_t* Ng = nprev + (size_t)b * TT * NPREV;

  // stage chunk 0
#pragma unroll
  for (int i = 0; i < 8; ++i) {
    int off = (wv * 8 + i) * 1024;
    GLDS(Mg + off + lane * 16, (uint8_t*)Ml[0] + off);
  }
  if (wv == 0) GLDS(Ng + lane * 16, Nl[0]);

  float beta = fminf(1.0f, fmaxf(0.0f, *pbeta));
  const double DSCALE = (double)SCALE_F;
  const double DWMIN  = (double)0.001f;
  float mem = 0.0f;
  for (int c = 0; c < 8; ++c) {
    __syncthreads();                       // drain: buf[c&1] staged, prev compute done
    if (c < 7) {
      int t0 = (c + 1) * 64;
#pragma unroll
      for (int i = 0; i < 8; ++i) {
        int off = (wv * 8 + i) * 1024;
        GLDS(Mg + (size_t)t0 * 256 + off + lane * 16, (uint8_t*)Ml[(c + 1) & 1] + off);
      }
      if (wv == 0) GLDS(Ng + (size_t)t0 * NPREV + lane * 16, Nl[(c + 1) & 1]);
    }
    const uint16_t* ml = Ml[c & 1];
    const uint8_t*  nl = Nl[c & 1];
    int jn = (c == 7) ? 52 : 64;
    for (int j = 0; j < jn; ++j) {
      int t = c * 64 + j;
      int m = ml[j * 128 + tid];
      int n;
      if (NPREV == 4) n = bsum4(((const uint32_t*)nl)[j]);
      else { uint32_t w0 = ((const uint32_t*)nl)[j * 2], w1 = ((const uint32_t*)nl)[j * 2 + 1];
             n = bsum4(w0) + bsum4(w1); }
      float cur = (float)((double)m * DSCALE + (double)n * DWMIN);
      int   rs  = (mem > 1.0f);
      float t2  = __fadd_rn(__fmul_rn(beta, mem), cur);
      mem = rs ? __fsub_rn(t2, 1.0f) : t2;
      int spk = (mem > 1.0f);
      spk_out[(size_t)t * (BB * HD) + b * HD + h] = spk ? 1.0f : 0.0f;
      s_out[((size_t)b * TT + t) * HD + h] = spk ? 0x3F80 : 0;
      unsigned long long bal = __ballot(spk);
      if (lane == 0) n8[((size_t)b * TT + t) * 8 + wv_g] = (uint8_t)__popcll(bal);
    }
  }
}

// ---------------- LIF scan, layer 4: 64 blocks (b) x 128 thr, M4[row][64] b-major
__global__ __launch_bounds__(128) void k_scanl4(const uint16_t* __restrict__ M4,
                                                const uint8_t* __restrict__ nprev,
                                                const float* __restrict__ pbeta,
                                                float* __restrict__ spk_out,
                                                float* __restrict__ mem_out) {
  __shared__ uint16_t Ml[2][64 * 64];    // 2 x 8 KB
  __shared__ uint8_t  Nl[2][1024];
  int tid = threadIdx.x;
  int b = blockIdx.x;
  int wv = tid >> 6, lane = tid & 63;
  const uint8_t* Mg = (const uint8_t*)M4 + (size_t)b * TT * 128;
  const uint8_t* Ng = nprev + (size_t)b * TT * 8;

#pragma unroll
  for (int i = 0; i < 4; ++i) {
    int off = (wv * 4 + i) * 1024;
    GLDS(Mg + off + lane * 16, (uint8_t*)Ml[0] + off);
  }
  if (wv == 0) GLDS(Ng + lane * 16, Nl[0]);

  float beta = fminf(1.0f, fmaxf(0.0f, *pbeta));
  const double DSCALE = (double)SCALE_F;
  const double DWMIN  = (double)0.001f;
  float mem = 0.0f;
  for (int c = 0; c < 8; ++c) {
    __syncthreads();
    if (c < 7) {
      int t0 = (c + 1) * 64;
#pragma unroll
      for (int i = 0; i < 4; ++i) {
        int off = (wv * 4 + i) * 1024;
        GLDS(Mg + (size_t)t0 * 128 + off + lane * 16, (uint8_t*)Ml[(c + 1) & 1] + off);
      }
      if (wv == 0) GLDS(Ng + (size_t)t0 * 8 + lane * 16, Nl[(c + 1) & 1]);
    }
    const uint16_t* ml = Ml[c & 1];
    const uint8_t*  nl = Nl[c & 1];
    int jn = (c == 7) ? 52 : 64;
    if (tid < 35) {
      for (int j = 0; j < jn; ++j) {
        int t = c * 64 + j;
        int m = ml[j * 64 + tid];
        uint32_t w0 = ((const uint32_t*)nl)[j * 2], w1 = ((const uint32_t*)nl)[j * 2 + 1];
        int n = bsum4(w0) + bsum4(w1);
        float cur = (float)((double)m * DSCALE + (double)n * DWMIN);
        int   rs  = (mem > 1.0f);
        float t2  = __fadd_rn(__fmul_rn(beta, mem), cur);
        mem = rs ? __fsub_rn(t2, 1.0f) : t2;
        int spk = (mem > 1.0f);
        spk_out[(size_t)t * (BB * 35) + b * 35 + tid] = spk ? 1.0f : 0.0f;
        mem_out[(size_t)t * (BB * 35) + b * 35 + tid] = mem;
      }
    }
  }
}

// ---------------- launch
extern "C" void kernel_launch(void* const* d_in, const int* in_sizes, int n_in,
                              void* d_out, int out_size, void* d_ws, size_t ws_size,
                              hipStream_t stream) {
  const float* x      = (const float*)d_in[0];
  const float* Wch    = (const float*)d_in[1];
  const float* W1     = (const float*)d_in[2];
  const float* W2     = (const float*)d_in[3];
  const float* W3     = (const float*)d_in[4];
  const float* W4     = (const float*)d_in[5];
  const float* cbetas = (const float*)d_in[6];
  const float* b1     = (const float*)d_in[7];
  const float* b2     = (const float*)d_in[8];
  const float* b3     = (const float*)d_in[9];
  const float* b4     = (const float*)d_in[10];

  uint8_t* ws = (uint8_t*)d_ws;
  uint16_t* wk1  = (uint16_t*)(ws + 0);          // 512*256*2
  uint16_t* wk2  = (uint16_t*)(ws + 262144);     // 512*512*2
  uint16_t* wk3  = (uint16_t*)(ws + 786432);
  uint16_t* wk4  = (uint16_t*)(ws + 1310720);    // 64*512*2
  uint8_t*  n4c  = (uint8_t*)(ws + 1441792);     // 128000 + 1K pad
  uint8_t*  n1   = (uint8_t*)(ws + 1570816);     // 256000 + 1K pad
  uint8_t*  n2   = (uint8_t*)(ws + 1827840);
  uint8_t*  n3   = (uint8_t*)(ws + 2084864);     // ends 2341888
  uint16_t* chs  = (uint16_t*)(ws + 2341888);    // 16384000
  uint16_t* sbuf = (uint16_t*)(ws + 18725888);   // 32768000
  uint16_t* mbuf = (uint16_t*)(ws + 51493888);   // 32768000 + 4K pad

  float* out  = (float*)d_out;
  float* spk1 = out;
  float* spk2 = out + 16384000;
  float* spk3 = out + 32768000;
  float* spk4 = out + 49152000;
  float* mem4 = out + 50272000;

  k_prep_coch<<<2880, 256, 0, stream>>>(W1, W2, W3, W4, wk1, wk2, wk3, wk4,
                                        x, Wch, cbetas, chs, n4c);

  k_gemm_lds<256><<<1000, 256, 0, stream>>>(chs, wk1, mbuf, 4);
  k_scan512<4><<<256, 128, 0, stream>>>(mbuf, n4c, b1, spk1, sbuf, n1);

  k_gemm_lds<512><<<1000, 256, 0, stream>>>(sbuf, wk2, mbuf, 4);
  k_scan512<8><<<256, 128, 0, stream>>>(mbuf, n1, b2, spk2, sbuf, n2);

  k_gemm_lds<512><<<1000, 256, 0, stream>>>(sbuf, wk3, mbuf, 4);
  k_scan512<8><<<256, 128, 0, stream>>>(mbuf, n2, b3, spk3, sbuf, n3);

  k_gemm_naive<512><<<125, 256, 0, stream>>>(sbuf, wk4, mbuf);
  k_scanl4<<<64, 128, 0, stream>>>(mbuf, n3, b4, spk4, mem4);
}